// Round 7
// baseline (121.384 us; speedup 1.0000x reference)
//
#include <hip/hip_runtime.h>

#define K_ELL 32    // main ELL planes (column-major)
#define K_OVF 32    // overflow ELL planes (out-of-band fallback; expected ~empty)
#define BS    256
#define TBS   1024  // transpose block size
#define RNG   8192  // a-range width per transpose block
#define BAND  8192  // assumed max (b-a); edges beyond fall back to global atomics
#define RW    (RNG + BAND)

// offs_a[u] = first edge index with a >= u (edges[:,0] sorted ascending, a<b,
// guaranteed by np.unique(np.sort(e,1),axis=0)). offs_a has V+1 entries.
__global__ void bound_kernel(const int2* __restrict__ edges, int* __restrict__ offs_a,
                             int E, int V) {
    int i = blockIdx.x * blockDim.x + threadIdx.x;
    if (i < E) {
        int lo = (i == 0) ? 0 : edges[i - 1].x + 1;
        int hi = edges[i].x;
        for (int a = lo; a <= hi; a++) offs_a[a] = i;
    } else if (i == E) {
        for (int a = edges[E - 1].x + 1; a <= V; a++) offs_a[a] = E;
    }
}

// Pass 1: per-block LDS histogram of b over [v0+1, v0+RNG+BAND].
// near (rel<RNG) -> cntN[u]; far -> cntF[u]. Out-of-band: global-atomic fallback
// directly into overflow planes. Extra blocks (>= NBb) do faces->float + v->float4.
__global__ __launch_bounds__(TBS) void count_kernel(
        const int2* __restrict__ edges, const int* __restrict__ offs_a,
        int* __restrict__ cntN, int* __restrict__ cntF,
        int* __restrict__ deg_ovf, int* __restrict__ adj_ovf,
        const int* __restrict__ faces, float* __restrict__ out_f,
        const float* __restrict__ v, float4* __restrict__ v4,
        int E, int V, int F3, int NBb) {
    __shared__ int cnt[RW];
    if ((int)blockIdx.x >= NBb) {
        int t = (blockIdx.x - NBb) * TBS + threadIdx.x;
        int T = (gridDim.x - NBb) * TBS;
        for (int j = t; j < F3; j += T) out_f[j] = (float)faces[j];
        for (int u = t; u < V; u += T)
            v4[u] = make_float4(v[3 * u], v[3 * u + 1], v[3 * u + 2], 0.f);
        return;
    }
    const int v0 = blockIdx.x * RNG;
    for (int i = threadIdx.x; i < RW; i += TBS) cnt[i] = 0;
    __syncthreads();
    const int vEnd = min(v0 + RNG, V);
    const int eBeg = offs_a[v0], eEnd = offs_a[vEnd];
    for (int i = eBeg + threadIdx.x; i < eEnd; i += TBS) {
        int2 e = edges[i];
        int rel = e.y - (v0 + 1);          // b > a >= v0 -> rel >= 0
        if (rel < RW) {
            atomicAdd(&cnt[rel], 1);       // LDS atomic (fast)
        } else {                            // out-of-band fallback (expected rare)
            int r = atomicAdd(&deg_ovf[e.y], 1);
            if (r < K_OVF) adj_ovf[(size_t)r * V + e.y] = e.x;
        }
    }
    __syncthreads();
    for (int i = threadIdx.x; i < RW; i += TBS) {
        int u = v0 + 1 + i;
        if (u <= V) {
            if (i < RNG) cntN[u] = cnt[i];
            else         cntF[u] = cnt[i];
        }
    }
}

// Pass 2: re-derive LDS ranks (order may differ; only uniqueness matters) and
// fill main ELL planes. Far block owns slots [0,cntF), near block [cntF,cntF+cntN).
__global__ __launch_bounds__(TBS) void fill_kernel(
        const int2* __restrict__ edges, const int* __restrict__ offs_a,
        const int* __restrict__ cntF, int* __restrict__ adj, int V) {
    __shared__ int cnt[RW];
    const int v0 = blockIdx.x * RNG;
    for (int i = threadIdx.x; i < RW; i += TBS) cnt[i] = 0;
    __syncthreads();
    const int vEnd = min(v0 + RNG, V);
    const int eBeg = offs_a[v0], eEnd = offs_a[vEnd];
    for (int i = eBeg + threadIdx.x; i < eEnd; i += TBS) {
        int2 e = edges[i];
        int rel = e.y - (v0 + 1);
        if (rel < RW) {
            int r = atomicAdd(&cnt[rel], 1);
            int slot = (rel < RNG) ? (cntF[e.y] + r) : r;   // near after far
            if (slot < K_ELL) adj[(size_t)slot * V + e.y] = e.x;
        }
        // out-of-band edges already fully handled in count_kernel
    }
}

// One smoothing iteration (lambd==1 -> y = nbr_sum/deg; deg==0 -> 0, matches ref).
template <bool PAD>
__global__ void gather_kernel(const float4* __restrict__ x4, const int2* __restrict__ edges,
                              const int* __restrict__ offs_a,
                              const int* __restrict__ cntN, const int* __restrict__ cntF,
                              const int* __restrict__ deg_ovf,
                              const int* __restrict__ adj, const int* __restrict__ adj_ovf,
                              float* __restrict__ y, int V) {
    int u = blockIdx.x * blockDim.x + threadIdx.x;
    if (u >= V) return;
    int aBeg = offs_a[u], aEnd = offs_a[u + 1];
    int dm  = cntN[u] + cntF[u];
    int dgo = deg_ovf[u];
    float s0 = 0.f, s1 = 0.f, s2 = 0.f;
    for (int i = aBeg; i < aEnd; i++) {
        float4 p = x4[edges[i].y];
        s0 += p.x; s1 += p.y; s2 += p.z;
    }
    int dmc = dm > K_ELL ? K_ELL : dm;
    for (int k = 0; k < dmc; k++) {
        float4 p = x4[adj[(size_t)k * V + u]];    // coalesced plane reads
        s0 += p.x; s1 += p.y; s2 += p.z;
    }
    int doc = dgo > K_OVF ? K_OVF : dgo;
    for (int k = 0; k < doc; k++) {               // expected empty
        float4 p = x4[adj_ovf[(size_t)k * V + u]];
        s0 += p.x; s1 += p.y; s2 += p.z;
    }
    int d = (aEnd - aBeg) + dm + dgo;
    float inv = 1.0f / fmaxf((float)d, 1.0f);
    if (PAD) {
        ((float4*)y)[u] = make_float4(s0 * inv, s1 * inv, s2 * inv, 0.f);
    } else {
        y[3 * u + 0] = s0 * inv;
        y[3 * u + 1] = s1 * inv;
        y[3 * u + 2] = s2 * inv;
    }
}

extern "C" void kernel_launch(void* const* d_in, const int* in_sizes, int n_in,
                              void* d_out, int out_size, void* d_ws, size_t ws_size,
                              hipStream_t stream) {
    const float* v     = (const float*)d_in[0];  // [V,3]
    const int2*  edges = (const int2*)d_in[1];   // [E,2], rows lex-sorted, a<b
    const int*   faces = (const int*)d_in[2];    // [F,3]

    const int V3 = in_sizes[0];
    const int V  = V3 / 3;
    const int E  = in_sizes[1] / 2;
    const int F3 = in_sizes[2];

    float* out_v = (float*)d_out;
    float* out_f = (float*)d_out + V3;

    // ws layout (16B-aligned first): v4[V] | x1[V] (float4) | adj[K_ELL*V] |
    //   adj_ovf[K_OVF*V] | offs_a[V+1] | cntN[V+1] | cntF[V+1] | deg_ovf[V]
    float4* v4      = (float4*)d_ws;
    float4* x1      = v4 + V;
    int*    adj     = (int*)(x1 + V);
    int*    adj_ovf = adj + (size_t)K_ELL * V;
    int*    offs_a  = adj_ovf + (size_t)K_OVF * V;
    int*    cntN    = offs_a + (V + 1);
    int*    cntF    = cntN + (V + 1);
    int*    deg_ovf = cntF + (V + 1);

    const int NBb = (V + RNG - 1) / RNG;                 // transpose blocks
    const int copyElems = F3 > V ? F3 : V;
    const int NBc = (copyElems + TBS - 1) / TBS;         // copy blocks
    const int gBound = (E + 1 + BS - 1) / BS;
    const int gV = (V + BS - 1) / BS;

    // zero cntN | cntF | deg_ovf (contiguous); ws is poisoned 0xAA each call
    hipMemsetAsync(cntN, 0, (size_t)(3 * V + 2) * sizeof(int), stream);

    bound_kernel<<<gBound, BS, 0, stream>>>(edges, offs_a, E, V);

    count_kernel<<<NBb + NBc, TBS, 0, stream>>>(edges, offs_a, cntN, cntF,
                                                deg_ovf, adj_ovf, faces, out_f,
                                                v, v4, E, V, F3, NBb);

    fill_kernel<<<NBb, TBS, 0, stream>>>(edges, offs_a, cntF, adj, V);

    gather_kernel<true ><<<gV, BS, 0, stream>>>(v4, edges, offs_a, cntN, cntF, deg_ovf,
                                                adj, adj_ovf, (float*)x1, V);
    gather_kernel<false><<<gV, BS, 0, stream>>>(x1, edges, offs_a, cntN, cntF, deg_ovf,
                                                adj, adj_ovf, out_v, V);
}

// Round 8
// 109.582 us; speedup vs baseline: 1.1077x; 1.1077x over previous
//
#include <hip/hip_runtime.h>

#define K_ELL 32    // ELL planes per near/far array (column-major; unused planes = 0 traffic)
#define K_OVF 16    // overflow planes (out-of-band fallback, expected ~empty)
#define BS    256
#define TBS   1024  // build block size
#define RNG   4096  // a-range per build block
#define BAND  4096  // max in-band (b - block_base); must be <= RNG for unique far owner
#define RW    (RNG + BAND)   // 8192 ints = 32 KB LDS

// Single-pass build. Heavy blocks (< NBb): per-vertex b-side adjacency via LDS-rank
// atomics into column-major ELL (near/far split by owner block), plus offs_a fill
// (edges[:,0] sorted ascending, a<b, guaranteed by np.unique(np.sort(e,1),axis=0)).
// Copy blocks (>= NBb): faces->float and v->float4 repack.
__global__ __launch_bounds__(TBS) void build_kernel(
        const int2* __restrict__ edges, int* __restrict__ offs_a,
        int* __restrict__ cntN, int* __restrict__ cntF, int* __restrict__ deg_ovf,
        int* __restrict__ adjN, int* __restrict__ adjF, int* __restrict__ adj_ovf,
        const int* __restrict__ faces, float* __restrict__ out_f,
        const float* __restrict__ v, float4* __restrict__ v4,
        int E, int V, int F3, int NBb) {
    if ((int)blockIdx.x >= NBb) {
        int t = (blockIdx.x - NBb) * TBS + threadIdx.x;
        int T = (gridDim.x - NBb) * TBS;
        for (int j = t; j < F3; j += T) out_f[j] = (float)faces[j];
        for (int u = t; u < V; u += T)
            v4[u] = make_float4(v[3 * u], v[3 * u + 1], v[3 * u + 2], 0.f);
        return;
    }
    __shared__ int cnt[RW];
    const int v0   = blockIdx.x * RNG;
    const int vEnd = min(v0 + RNG, V);
    for (int i = threadIdx.x; i < RW; i += TBS) cnt[i] = 0;

    // binary-search this block's edge span (uniform across threads, no divergence)
    int lo = 0, hi = E;
    while (lo < hi) { int m = (lo + hi) >> 1; if (edges[m].x < v0) lo = m + 1; else hi = m; }
    const int eBeg = lo;
    hi = E;
    while (lo < hi) { int m = (lo + hi) >> 1; if (edges[m].x < vEnd) lo = m + 1; else hi = m; }
    const int eEnd = lo;
    __syncthreads();

    for (int i = eBeg + threadIdx.x; i < eEnd; i += TBS) {
        int2 e = edges[i];
        // offs_a[a] = first edge index with edges[.].x >= a
        int plo = (i == 0) ? 0 : edges[i - 1].x + 1;
        for (int a = plo; a <= e.x; a++) offs_a[a] = i;
        int rel = e.y - (v0 + 1);            // b > a >= v0  ->  rel >= 0
        if (rel < RW) {
            int r = atomicAdd(&cnt[rel], 1); // LDS-rank: final slot, no global atomics
            if (rel < RNG) { if (r < K_ELL) adjN[(size_t)r * V + e.y] = e.x; }
            else           { if (r < K_ELL) adjF[(size_t)r * V + e.y] = e.x; }
        } else {                              // out-of-band fallback (rare/none)
            int r = atomicAdd(&deg_ovf[e.y], 1);
            if (r < K_OVF) adj_ovf[(size_t)r * V + e.y] = e.x;
        }
    }
    if ((int)blockIdx.x == NBb - 1) {        // offs_a tail: a in (edges[E-1].x, V]
        int lastA = edges[E - 1].x;
        for (int a = lastA + 1 + threadIdx.x; a <= V; a += TBS) offs_a[a] = E;
    }
    __syncthreads();
    for (int i = threadIdx.x; i < RW; i += TBS) {
        int u = v0 + 1 + i;
        if (u <= V) {
            if (i < RNG) cntN[u] = cnt[i];   // this block is u's unique near owner
            else         cntF[u] = cnt[i];   // ... unique far owner (BAND <= RNG)
        }
    }
}

// One smoothing iteration (lambd==1 -> y = nbr_sum/deg; deg==0 -> 0, matches ref).
template <bool PAD>
__global__ void gather_kernel(const float4* __restrict__ x4, const int2* __restrict__ edges,
                              const int* __restrict__ offs_a,
                              const int* __restrict__ cntN, const int* __restrict__ cntF,
                              const int* __restrict__ deg_ovf,
                              const int* __restrict__ adjN, const int* __restrict__ adjF,
                              const int* __restrict__ adj_ovf,
                              float* __restrict__ y, int V) {
    int u = blockIdx.x * blockDim.x + threadIdx.x;
    if (u >= V) return;
    int aBeg = offs_a[u], aEnd = offs_a[u + 1];
    int cN = cntN[u], cF = cntF[u], dO = deg_ovf[u];
    float s0 = 0.f, s1 = 0.f, s2 = 0.f;
    for (int i = aBeg; i < aEnd; i++) {
        float4 p = x4[edges[i].y];
        s0 += p.x; s1 += p.y; s2 += p.z;
    }
    int kN = cN > K_ELL ? K_ELL : cN;
    for (int k = 0; k < kN; k++) {
        float4 p = x4[adjN[(size_t)k * V + u]];   // coalesced plane reads
        s0 += p.x; s1 += p.y; s2 += p.z;
    }
    int kF = cF > K_ELL ? K_ELL : cF;
    for (int k = 0; k < kF; k++) {
        float4 p = x4[adjF[(size_t)k * V + u]];
        s0 += p.x; s1 += p.y; s2 += p.z;
    }
    int kO = dO > K_OVF ? K_OVF : dO;
    for (int k = 0; k < kO; k++) {                // expected empty
        float4 p = x4[adj_ovf[(size_t)k * V + u]];
        s0 += p.x; s1 += p.y; s2 += p.z;
    }
    int d = (aEnd - aBeg) + cN + cF + dO;
    float inv = 1.0f / fmaxf((float)d, 1.0f);
    if (PAD) {
        ((float4*)y)[u] = make_float4(s0 * inv, s1 * inv, s2 * inv, 0.f);
    } else {
        y[3 * u + 0] = s0 * inv;
        y[3 * u + 1] = s1 * inv;
        y[3 * u + 2] = s2 * inv;
    }
}

extern "C" void kernel_launch(void* const* d_in, const int* in_sizes, int n_in,
                              void* d_out, int out_size, void* d_ws, size_t ws_size,
                              hipStream_t stream) {
    const float* v     = (const float*)d_in[0];  // [V,3]
    const int2*  edges = (const int2*)d_in[1];   // [E,2], rows lex-sorted, a<b
    const int*   faces = (const int*)d_in[2];    // [F,3]

    const int V3 = in_sizes[0];
    const int V  = V3 / 3;
    const int E  = in_sizes[1] / 2;
    const int F3 = in_sizes[2];

    float* out_v = (float*)d_out;
    float* out_f = (float*)d_out + V3;

    // ws layout (16B-aligned first): v4[V] | x1[V] (float4) | adjN[K_ELL*V] |
    //   adjF[K_ELL*V] | adj_ovf[K_OVF*V] | offs_a[V+1] | cntN[V+1] | cntF[V+1] | deg_ovf[V]
    float4* v4      = (float4*)d_ws;
    float4* x1      = v4 + V;
    int*    adjN    = (int*)(x1 + V);
    int*    adjF    = adjN + (size_t)K_ELL * V;
    int*    adj_ovf = adjF + (size_t)K_ELL * V;
    int*    offs_a  = adj_ovf + (size_t)K_OVF * V;
    int*    cntN    = offs_a + (V + 1);
    int*    cntF    = cntN + (V + 1);
    int*    deg_ovf = cntF + (V + 1);

    const int NBb = (V + RNG - 1) / RNG;                 // heavy build blocks (~46)
    const int copyElems = F3 > V ? F3 : V;
    const int NBc = (copyElems + TBS - 1) / TBS;         // copy blocks (~1100)
    const int gV  = (V + BS - 1) / BS;

    // zero cntN | cntF | deg_ovf (contiguous; offs_a is fully written by build)
    hipMemsetAsync(cntN, 0, (size_t)(3 * V + 2) * sizeof(int), stream);

    build_kernel<<<NBb + NBc, TBS, 0, stream>>>(edges, offs_a, cntN, cntF, deg_ovf,
                                                adjN, adjF, adj_ovf, faces, out_f,
                                                v, v4, E, V, F3, NBb);

    gather_kernel<true ><<<gV, BS, 0, stream>>>(v4, edges, offs_a, cntN, cntF, deg_ovf,
                                                adjN, adjF, adj_ovf, (float*)x1, V);
    gather_kernel<false><<<gV, BS, 0, stream>>>(x1, edges, offs_a, cntN, cntF, deg_ovf,
                                                adjN, adjF, adj_ovf, out_v, V);
}